// Round 1
// baseline (141.017 us; speedup 1.0000x reference)
//
#include <hip/hip_runtime.h>

// Problem constants (from reference): D_MODEL=512, H=8, B=4, S=2048.
// Key insight: masked_fill(-1e9) happens BEFORE abs(), so softmax(abs(scores))
// puts ALL probability mass uniformly on positions where mask==0, independent
// of query/head. Output[b,s,:] = ((mean of value[b,k,:] over mask[b,k]==0) @ Wv.T + bv) @ Wo.T + bo,
// identical for every s. Q/K/Wq/bq/Wk/bk are dead inputs.

#define DM 512
#define SEQ 2048
#define NB 4

// ---------------------------------------------------------------------------
// Kernel A: per-batch sum of value rows where mask==0, plus count.
// grid = NB * 32 blocks (32 s-chunks of 64 rows each), 256 threads.
// Each thread accumulates 2 columns; atomicAdd partials to acc[b][512].
// ---------------------------------------------------------------------------
__global__ void masked_sum_kernel(const float* __restrict__ value,
                                  const int* __restrict__ mask,
                                  float* __restrict__ acc,
                                  int* __restrict__ cnt) {
    const int SCH = 32;
    const int ROWS = SEQ / SCH;  // 64
    int b   = blockIdx.x / SCH;
    int sc  = blockIdx.x % SCH;
    int col = threadIdx.x;       // handles col and col+256
    const float* vb = value + (size_t)b * SEQ * DM;
    const int*   mb = mask + b * SEQ;
    float s0 = 0.f, s1 = 0.f;
    int c = 0;
    int sbeg = sc * ROWS;
    for (int s = sbeg; s < sbeg + ROWS; ++s) {
        if (mb[s] == 0) {  // uniform branch across the block (scalar)
            const float* row = vb + (size_t)s * DM;
            s0 += row[col];
            s1 += row[col + 256];
            ++c;
        }
    }
    atomicAdd(&acc[b * DM + col], s0);
    atomicAdd(&acc[b * DM + col + 256], s1);
    if (col == 0) atomicAdd(&cnt[b], c);
}

// ---------------------------------------------------------------------------
// Kernel B: y[b][d] = bias[d] + sum_i (x[b][i]*scale) * W[d][i]
// scale = 1/cnt[b] if use_cnt else 1.  W is [DM, DM] row-major (torch x@W.T).
// grid = (8 dim-slices of 64, NB), 256 threads = 4 waves; each wave does a
// dim at a time with coalesced 64-lane row reads + shuffle reduction.
// ---------------------------------------------------------------------------
__global__ void matvec_kernel(const float* __restrict__ x,
                              const int* __restrict__ cnt,
                              const float* __restrict__ W,
                              const float* __restrict__ bias,
                              float* __restrict__ y,
                              int use_cnt) {
    __shared__ float xs[DM];
    int b = blockIdx.y;
    float scale = use_cnt ? (1.0f / (float)cnt[b]) : 1.0f;
    for (int i = threadIdx.x; i < DM; i += blockDim.x)
        xs[i] = x[b * DM + i] * scale;
    __syncthreads();

    int lane = threadIdx.x & 63;
    int wave = threadIdx.x >> 6;
    int dbase = blockIdx.x * 64;
    for (int j = wave; j < 64; j += 4) {
        int d = dbase + j;
        const float* wrow = W + (size_t)d * DM;
        float sum = 0.f;
#pragma unroll
        for (int i = 0; i < DM / 64; ++i)
            sum += wrow[i * 64 + lane] * xs[i * 64 + lane];
#pragma unroll
        for (int off = 32; off; off >>= 1)
            sum += __shfl_down(sum, off);
        if (lane == 0) y[b * DM + d] = sum + bias[d];
    }
}

// ---------------------------------------------------------------------------
// Kernel C: broadcast z[b][512] to out[b][s][512] for all s. float4 stores.
// Total float4 elements: NB*SEQ*DM/4 = 2^20; 2^18 per batch, 128 per row.
// ---------------------------------------------------------------------------
__global__ void broadcast_kernel(const float* __restrict__ z,
                                 float4* __restrict__ out) {
    const int TOT4 = NB * SEQ * DM / 4;  // 1048576
    const float4* z4 = (const float4*)z;
    int idx = blockIdx.x * blockDim.x + threadIdx.x;
    int stride = gridDim.x * blockDim.x;
    for (int i = idx; i < TOT4; i += stride) {
        int b  = i >> 18;   // SEQ*DM/4 = 262144 float4 per batch
        int d4 = i & 127;   // DM/4 float4 per row
        out[i] = z4[b * 128 + d4];
    }
}

extern "C" void kernel_launch(void* const* d_in, const int* in_sizes, int n_in,
                              void* d_out, int out_size, void* d_ws, size_t ws_size,
                              hipStream_t stream) {
    // Input order: query,key,value,mask,Wq,bq,Wk,bk,Wv,bv,Wo,bo
    const float* value = (const float*)d_in[2];
    const int*   mask  = (const int*)d_in[3];
    const float* Wv    = (const float*)d_in[8];
    const float* bv    = (const float*)d_in[9];
    const float* Wo    = (const float*)d_in[10];
    const float* bo    = (const float*)d_in[11];
    float* out = (float*)d_out;

    // Workspace layout: acc[NB*DM] | y[NB*DM] | z[NB*DM] | cnt[NB]
    float* acc = (float*)d_ws;
    float* y   = acc + NB * DM;
    float* z   = y + NB * DM;
    int*   cnt = (int*)(z + NB * DM);
    size_t ws_used = (size_t)(3 * NB * DM) * sizeof(float) + NB * sizeof(int);

    hipMemsetAsync(d_ws, 0, ws_used, stream);

    masked_sum_kernel<<<dim3(NB * 32), dim3(256), 0, stream>>>(value, mask, acc, cnt);
    matvec_kernel<<<dim3(8, NB), dim3(256), 0, stream>>>(acc, cnt, Wv, bv, y, 1);
    matvec_kernel<<<dim3(8, NB), dim3(256), 0, stream>>>(y, cnt, Wo, bo, z, 0);
    broadcast_kernel<<<dim3(1024), dim3(256), 0, stream>>>(z, (float4*)out);
}